// Round 8
// baseline (308.172 us; speedup 1.0000x reference)
//
#include <hip/hip_runtime.h>
#include <math.h>

// Problem constants
constexpr int B_  = 128;
constexpr int S_  = 256;
constexpr int D_  = 128;   // d_model
constexpr int H_  = 8;
constexpr int DK_ = 16;
constexpr int SK_ = 30;    // SAMPLE_K
constexpr int NT_ = 30;    // N_TOP

typedef short short8  __attribute__((ext_vector_type(8)));
typedef float floatx4 __attribute__((ext_vector_type(4)));

__device__ inline ushort bf16_rne(float f) {
    unsigned u = __float_as_uint(f);
    u += 0x7fffu + ((u >> 16) & 1u);
    return (ushort)(u >> 16);
}
__device__ inline float bf16_to_f(ushort h) {
    return __uint_as_float(((unsigned)h) << 16);
}

// ---------------------------------------------------------------------------
// K0: W prep + trig, t-major (unchanged from R7).
// ---------------------------------------------------------------------------
__global__ __launch_bounds__(256) void wprep_kernel(
    const float* __restrict__ wk, const float* __restrict__ wv,
    const float* __restrict__ lw,
    ushort* __restrict__ wk_hi, ushort* __restrict__ wk_lo,
    ushort* __restrict__ wv_hi,
    ushort* __restrict__ lw_hi, ushort* __restrict__ lw_lo,
    float* __restrict__ trig)
{
    int tid = blockIdx.x * 256 + threadIdx.x;   // grid 1920 -> 0..491519
    if (tid < 458752) {                         // 7*65536 conv weights
        int t  = tid >> 16;                     // 0..6
        int oi = tid & 65535;                   // o*256 + i
        float fk = wk[(size_t)oi * 7 + t];
        ushort hk = bf16_rne(fk);
        wk_hi[tid] = hk;                        // tid == t*65536 + oi
        wk_lo[tid] = bf16_rne(fk - bf16_to_f(hk));
        wv_hi[tid] = bf16_rne(wv[(size_t)oi * 7 + t]);
    } else if (tid < 475136) {                  // lin_w
        int ec = tid - 458752;                  // e*128 + c
        float f = lw[ec];
        ushort hi = bf16_rne(f);
        lw_hi[ec] = hi;
        lw_lo[ec] = bf16_rne(f - bf16_to_f(hi));
    } else {                                    // trig table (double)
        int t2 = tid - 475136;                  // 0..16383
        int f = t2 & 63, l = t2 >> 6;
        double freq = exp(((double)(-f) / 64.0) * 9.210340371976184); // ln(1e4)
        double ang  = (double)l * freq;
        trig[t2 * 2]     = (float)cos(ang);
        trig[t2 * 2 + 1] = (float)sin(ang);
    }
}

// ---------------------------------------------------------------------------
// K1: fused rotary + transpose + bf16 hi/lo convert (unchanged from R7).
// ---------------------------------------------------------------------------
__global__ __launch_bounds__(256) void rotcvt_kernel(
    const float* __restrict__ q, const float* __restrict__ k,
    const float* __restrict__ value, const float* __restrict__ trig,
    float* __restrict__ q_h,
    ushort* __restrict__ khi_t, ushort* __restrict__ klo_t,
    ushort* __restrict__ vhi_t)
{
    __shared__ float tile[64 * 132];   // 64 l x 128 d, pad 4
    int b  = blockIdx.x;
    int lc = blockIdx.y;               // l-chunk of 64
    int ph = blockIdx.z;               // 0=q, 1=k, 2=v
    int tid = threadIdx.x;

    if (ph == 0) {
        for (int s = tid; s < 2048; s += 256) {
            int l = s >> 5, c4 = s & 31;
            int lg = lc * 64 + l;
            float4 qv = *(const float4*)(q + (((size_t)b * 256) + lg) * 128 + c4 * 4);
            float4 tg = *(const float4*)(trig + ((size_t)lg * 64 + 2 * c4) * 2);
            float r0 = qv.x * tg.x - qv.y * tg.y;
            float i0 = qv.x * tg.y + qv.y * tg.x;
            float r1 = qv.z * tg.z - qv.w * tg.w;
            float i1 = qv.z * tg.w + qv.w * tg.z;
            int h = c4 >> 2, dk = (c4 & 3) * 4;
            *(float4*)(q_h + (((size_t)b * 8 + h) * 256 + lg) * 16 + dk) =
                make_float4(r0, i0, r1, i1);
        }
        return;
    }

    if (ph == 1) {
        for (int s = tid; s < 2048; s += 256) {
            int l = s >> 5, c4 = s & 31;
            int lg = lc * 64 + l;
            float4 kv = *(const float4*)(k + (((size_t)b * 256) + lg) * 128 + c4 * 4);
            float4 tg = *(const float4*)(trig + ((size_t)lg * 64 + 2 * c4) * 2);
            float r0 = kv.x * tg.x - kv.y * tg.y;
            float i0 = kv.x * tg.y + kv.y * tg.x;
            float r1 = kv.z * tg.z - kv.w * tg.w;
            float i1 = kv.z * tg.w + kv.w * tg.z;
            *(float4*)(tile + l * 132 + c4 * 4) = make_float4(r0, i0, r1, i1);
        }
        __syncthreads();
        int d = tid >> 1, half = tid & 1;
        alignas(16) ushort hh[32], ll[32];
#pragma unroll
        for (int j = 0; j < 32; j++) {
            float f = tile[(half * 32 + j) * 132 + d];
            ushort hb = bf16_rne(f);
            hh[j] = hb;
            ll[j] = bf16_rne(f - bf16_to_f(hb));
        }
        size_t off = (((size_t)b * 128) + d) * 256 + lc * 64 + half * 32;
#pragma unroll
        for (int m = 0; m < 4; m++) ((uint4*)(khi_t + off))[m] = ((uint4*)hh)[m];
#pragma unroll
        for (int m = 0; m < 4; m++) ((uint4*)(klo_t + off))[m] = ((uint4*)ll)[m];
        return;
    }

    // ph == 2: v
    for (int s = tid; s < 2048; s += 256) {
        int l = s >> 5, c4 = s & 31;
        *(float4*)(tile + l * 132 + c4 * 4) =
            *(const float4*)(value + (((size_t)b * 256) + lc * 64 + l) * 128 + c4 * 4);
    }
    __syncthreads();
    {
        int d = tid >> 1, half = tid & 1;
        alignas(16) ushort hh[32];
#pragma unroll
        for (int j = 0; j < 32; j++)
            hh[j] = bf16_rne(tile[(half * 32 + j) * 132 + d]);
        size_t off = (((size_t)b * 128) + d) * 256 + lc * 64 + half * 32;
#pragma unroll
        for (int m = 0; m < 4; m++) ((uint4*)(vhi_t + off))[m] = ((uint4*)hh)[m];
    }
}

// ---------------------------------------------------------------------------
// K2: conv6 = conv5 tiling + explicit software pipeline.
//  Same 64d x 64o wave tiles, same accumulation order (ic->ks->t, hh/lh/hl
//  per accumulator) -> k_h bitwise identical to R7 -> top-k stable.
//  New: W and A fragments for step N+1 are loaded into registers before
//  step N's 48-MFMA burst (forced prefetch; W crosses the ic barrier), and
//  the next ic's x-tile is prefetched into registers during compute.
// ---------------------------------------------------------------------------
__global__ __launch_bounds__(256, 2) void conv6_kernel(
    const ushort* __restrict__ khi_t, const ushort* __restrict__ klo_t,
    const ushort* __restrict__ vhi_t,
    const ushort* __restrict__ wk_hi, const ushort* __restrict__ wk_lo,
    const ushort* __restrict__ wv_hi,
    const float* __restrict__ kbias, const float* __restrict__ vbias,
    float* __restrict__ k_h, float* __restrict__ v_h)
{
    constexpr int LI = 72;                 // 64 i + 8 pad (16B-aligned rows)
    __shared__ ushort xhi[70 * LI];
    __shared__ ushort xlo[70 * LI];

    const bool kp = (blockIdx.z == 0);
    const ushort* xg   = kp ? khi_t : vhi_t;
    const ushort* whi  = kp ? wk_hi : wv_hi;
    const float*  bias = kp ? kbias : vbias;
    float* yh          = kp ? k_h : v_h;

    int b    = blockIdx.x;
    int dblk = blockIdx.y;                 // 64-d slice
    int tid  = threadIdx.x;
    int lane = tid & 63, wid = tid >> 6;   // wave owns o-range wid*64
    int lm = lane & 15, kb = lane >> 4;
    int obase = wid * 64;

    floatx4 acc[16];                       // [po(4)][nd(4)]
#pragma unroll
    for (int i = 0; i < 16; i++) acc[i] = (floatx4){0.f, 0.f, 0.f, 0.f};

    const short8 zero8 = {0, 0, 0, 0, 0, 0, 0, 0};

    // staging registers (x tile for the NEXT barrier), 3 chunks/thread
    short8 sh[3], sl[3];
    auto load_stage = [&](int ic) {
#pragma unroll
        for (int it = 0; it < 3; it++) {
            int s = tid + it * 256;
            int r = s >> 3, p = s & 7;
            int gd = dblk * 64 - 6 + r;
            bool ok = (s < 560) && (gd >= 0);
            size_t g = (((size_t)b * 128) + gd) * 256 + ic * 64 + p * 8;
            sh[it] = ok ? *(const short8*)(xg + g) : zero8;
            if (kp) sl[it] = ok ? *(const short8*)(klo_t + g) : zero8;
        }
    };
    auto store_stage = [&]() {
#pragma unroll
        for (int it = 0; it < 3; it++) {
            int s = tid + it * 256;
            if (s < 560) {
                int r = s >> 3, p = s & 7;
                *(short8*)(xhi + r * LI + p * 8) = sh[it];
                if (kp) *(short8*)(xlo + r * LI + p * 8) = sl[it];
            }
        }
    };
    auto load_w = [&](int ic, int ks, int t, short8* wh, short8* wl) {
        int ibase = ic * 64 + ks * 32 + kb * 8;
#pragma unroll
        for (int po = 0; po < 4; po++) {
            size_t woff = (size_t)t * 65536
                        + (size_t)(obase + po * 16 + lm) * 256 + ibase;
            wh[po] = *(const short8*)(whi + woff);
            if (kp) wl[po] = *(const short8*)(wk_lo + woff);
        }
    };
    auto load_a = [&](int ks, int t, short8* xh, short8* xl) {
#pragma unroll
        for (int nd = 0; nd < 4; nd++) {
            int arow = (nd * 16 + lm + t) * LI + ks * 32 + kb * 8;
            xh[nd] = *(const short8*)(xhi + arow);
            if (kp) xl[nd] = *(const short8*)(xlo + arow);
        }
    };

    short8 whc[4], wlc[4], whn[4], wln[4];
    short8 xhc[4], xlc[4], xhn[4], xln[4];

    load_stage(0);               // x tile for ic=0
    load_w(0, 0, 0, whc, wlc);   // W for step 0

#pragma unroll 1
    for (int ic = 0; ic < 4; ic++) {
        __syncthreads();
        store_stage();
        __syncthreads();
        if (ic < 3) load_stage(ic + 1);   // prefetch; consumed after next barrier
        load_a(0, 0, xhc, xlc);
#pragma unroll
        for (int step = 0; step < 14; step++) {
            int ks = step / 7, t = step % 7;
            (void)ks; (void)t;
            // prefetch operands for step+1 (W also across the ic boundary)
            if (step < 13) {
                int ns = step + 1;
                load_w(ic, ns / 7, ns % 7, whn, wln);
                load_a(ns / 7, ns % 7, xhn, xln);
            } else if (ic < 3) {
                load_w(ic + 1, 0, 0, whn, wln);
            }
            // MFMA burst — identical operand order to conv5
#pragma unroll
            for (int po = 0; po < 4; po++) {
#pragma unroll
                for (int nd = 0; nd < 4; nd++) {
                    int a = po * 4 + nd;
                    acc[a] = __builtin_amdgcn_mfma_f32_16x16x32_bf16(xhc[nd], whc[po], acc[a], 0, 0, 0);
                    if (kp) {
                        acc[a] = __builtin_amdgcn_mfma_f32_16x16x32_bf16(xlc[nd], whc[po], acc[a], 0, 0, 0);
                        acc[a] = __builtin_amdgcn_mfma_f32_16x16x32_bf16(xhc[nd], wlc[po], acc[a], 0, 0, 0);
                    }
                }
            }
            // rotate (SSA-renamed away by the unrolled step loop)
#pragma unroll
            for (int i2 = 0; i2 < 4; i2++) {
                whc[i2] = whn[i2]; wlc[i2] = wln[i2];
                xhc[i2] = xhn[i2]; xlc[i2] = xln[i2];
            }
        }
    }

    // epilogue: d = dblk*64 + nd*16 + kb*4 + r -> dhi = dblk*4+nd, dk = kb*4+r
#pragma unroll
    for (int po = 0; po < 4; po++) {
        int o = obase + po * 16 + lm;
        float bv = bias[o];
#pragma unroll
        for (int nd = 0; nd < 4; nd++) {
            int dhi = dblk * 4 + nd;
#pragma unroll
            for (int r = 0; r < 4; r++) {
                int dk = kb * 4 + r;
                yh[(((size_t)b * 8 + dhi) * 256 + o) * 16 + dk] = acc[po * 4 + nd][r] + bv;
            }
        }
    }
}

// ---------------------------------------------------------------------------
// K3: fused topk + attention + context assembly (unchanged from R7, passing).
// ---------------------------------------------------------------------------
__global__ __launch_bounds__(256) void topk_attn_kernel(
    const float* __restrict__ q_h, const float* __restrict__ k_h,
    const float* __restrict__ v_h, const int* __restrict__ idxs,
    ushort* __restrict__ ctx_hi, ushort* __restrict__ ctx_lo)
{
    __shared__ float ks[S_ * 20];
    __shared__ float vs[S_ * 20];
    __shared__ float Marr[S_];
    __shared__ float qs[NT_][16];
    __shared__ float partial[16][17];
    __shared__ float vmean_s[16];
    __shared__ int sel_s[NT_];
    __shared__ int selflag[S_];
    __shared__ int cnt;

    int bh = blockIdx.x, b = bh >> 3, h = bh & 7;
    int tid = threadIdx.x;
    if (tid == 0) cnt = 0;
    selflag[tid] = 0;

    const float* kp = k_h + (size_t)bh * S_ * DK_;
    const float* vp = v_h + (size_t)bh * S_ * DK_;
    for (int idx = tid; idx < S_ * DK_; idx += 256) {
        int r = idx >> 4, c = idx & 15;
        ks[r * 20 + c] = kp[idx];
        vs[r * 20 + c] = vp[idx];
    }

    float qr[16];
    const float4* qp = (const float4*)(q_h + ((size_t)bh * S_ + tid) * DK_);
#pragma unroll
    for (int i = 0; i < 4; i++) {
        float4 t4 = qp[i];
        qr[4*i] = t4.x; qr[4*i+1] = t4.y; qr[4*i+2] = t4.z; qr[4*i+3] = t4.w;
    }
    int idxr[SK_];
    const int* ip = idxs + tid * SK_;
#pragma unroll
    for (int s = 0; s < SK_; s++) idxr[s] = ip[s];
    __syncthreads();

    float mx = -1e30f, sm = 0.f;
#pragma unroll
    for (int s = 0; s < SK_; s++) {
        const float4* kr = (const float4*)(ks + idxr[s] * 20);
        float4 k0 = kr[0], k1 = kr[1], k2 = kr[2], k3 = kr[3];
        float d0 = qr[0]*k0.x, d1 = qr[1]*k0.y, d2 = qr[2]*k0.z, d3 = qr[3]*k0.w;
        d0 = fmaf(qr[4],  k1.x, d0); d1 = fmaf(qr[5],  k1.y, d1);
        d2 = fmaf(qr[6],  k1.z, d2); d3 = fmaf(qr[7],  k1.w, d3);
        d0 = fmaf(qr[8],  k2.x, d0); d1 = fmaf(qr[9],  k2.y, d1);
        d2 = fmaf(qr[10], k2.z, d2); d3 = fmaf(qr[11], k2.w, d3);
        d0 = fmaf(qr[12], k3.x, d0); d1 = fmaf(qr[13], k3.y, d1);
        d2 = fmaf(qr[14], k3.z, d2); d3 = fmaf(qr[15], k3.w, d3);
        float dot = (d0 + d1) + (d2 + d3);
        mx = fmaxf(mx, dot);
        sm += dot;
    }
    Marr[tid] = mx - sm * (1.0f / 30.0f);

    {
        int dk = tid & 15, chunk = tid >> 4;
        float s = 0.f;
#pragma unroll
        for (int r = 0; r < 16; r++) s += vs[(chunk * 16 + r) * 20 + dk];
        partial[chunk][dk] = s;
    }
    __syncthreads();

    if (tid < 16) {
        float s = 0.f;
#pragma unroll
        for (int c = 0; c < 16; c++) s += partial[c][tid];
        vmean_s[tid] = s * (1.0f / 256.0f);
    }
    {
        float M = Marr[tid];
        int higher = 0;
        for (int j = 0; j < S_; j++) {
            float Mj = Marr[j];
            if (Mj > M || (Mj == M && j < tid)) higher++;
        }
        if (higher < NT_) {
            int slot = atomicAdd(&cnt, 1);
            sel_s[slot] = tid;
            selflag[tid] = 1;
        }
    }
    __syncthreads();

    for (int idx = tid; idx < NT_ * 16; idx += 256) {
        int u = idx >> 4, c = idx & 15;
        qs[u][c] = q_h[((size_t)bh * S_ + sel_s[u]) * DK_ + c];
    }
    __syncthreads();

    if (!selflag[tid]) {
        alignas(16) ushort hh[16], ll[16];
#pragma unroll
        for (int i = 0; i < 16; i++) {
            float v = vmean_s[i];
            ushort hb = bf16_rne(v);
            hh[i] = hb;
            ll[i] = bf16_rne(v - bf16_to_f(hb));
        }
        size_t off = ((size_t)(b * S_ + tid)) * D_ + h * DK_;
        ((uint4*)(ctx_hi + off))[0] = ((uint4*)hh)[0];
        ((uint4*)(ctx_hi + off))[1] = ((uint4*)hh)[1];
        ((uint4*)(ctx_lo + off))[0] = ((uint4*)ll)[0];
        ((uint4*)(ctx_lo + off))[1] = ((uint4*)ll)[1];
    }

    int g = tid >> 3, j = tid & 7;
    if (g < NT_) {
        float qreg[16];
        const float4* q4 = (const float4*)qs[g];
#pragma unroll
        for (int i = 0; i < 4; i++) {
            float4 t4 = q4[i];
            qreg[4*i] = t4.x; qreg[4*i+1] = t4.y; qreg[4*i+2] = t4.z; qreg[4*i+3] = t4.w;
        }
        float e[32];
        float mxs = -1e30f;
#pragma unroll
        for (int li = 0; li < 32; li++) {
            int l = j + li * 8;
            const float4* kr = (const float4*)(ks + l * 20);
            float4 k0 = kr[0], k1 = kr[1], k2 = kr[2], k3 = kr[3];
            float d0 = qreg[0]*k0.x, d1 = qreg[1]*k0.y, d2 = qreg[2]*k0.z, d3 = qreg[3]*k0.w;
            d0 = fmaf(qreg[4],  k1.x, d0); d1 = fmaf(qreg[5],  k1.y, d1);
            d2 = fmaf(qreg[6],  k1.z, d2); d3 = fmaf(qreg[7],  k1.w, d3);
            d0 = fmaf(qreg[8],  k2.x, d0); d1 = fmaf(qreg[9],  k2.y, d1);
            d2 = fmaf(qreg[10], k2.z, d2); d3 = fmaf(qreg[11], k2.w, d3);
            d0 = fmaf(qreg[12], k3.x, d0); d1 = fmaf(qreg[13], k3.y, d1);
            d2 = fmaf(qreg[14], k3.z, d2); d3 = fmaf(qreg[15], k3.w, d3);
            e[li] = ((d0 + d1) + (d2 + d3)) * 0.25f;
            mxs = fmaxf(mxs, e[li]);
        }
        mxs = fmaxf(mxs, __shfl_xor(mxs, 1));
        mxs = fmaxf(mxs, __shfl_xor(mxs, 2));
        mxs = fmaxf(mxs, __shfl_xor(mxs, 4));
        float se = 0.f;
#pragma unroll
        for (int li = 0; li < 32; li++) {
            e[li] = __expf(e[li] - mxs);
            se += e[li];
        }
        se += __shfl_xor(se, 1);
        se += __shfl_xor(se, 2);
        se += __shfl_xor(se, 4);
        float inv = 1.0f / se;

        int dk0 = j * 2;
        int gbase = tid & 56;
        float o0 = 0.f, o1 = 0.f;
        for (int li = 0; li < 32; li++) {
#pragma unroll
            for (int m = 0; m < 8; m++) {
                float p = __shfl(e[li], gbase | m);
                float2 vv = *(const float2*)(vs + (li * 8 + m) * 20 + dk0);
                o0 = fmaf(p, vv.x, o0);
                o1 = fmaf(p, vv.y, o1);
            }
        }
        int lrow = sel_s[g];
        float v0 = o0 * inv, v1 = o1 * inv;
        ushort h0 = bf16_rne(v0), h1 = bf16_rne(v1);
        ushort l0 = bf16_rne(v0 - bf16_to_f(h0));
        ushort l1 = bf16_rne(v1 - bf16_to_f(h1));
        size_t off = ((size_t)(b * S_ + lrow)) * D_ + h * DK_ + dk0;
        *(uint*)(ctx_hi + off) = (uint)h0 | ((uint)h1 << 16);
        *(uint*)(ctx_lo + off) = (uint)l0 | ((uint)l1 << 16);
    }
}

// ---------------------------------------------------------------------------
// K4: final linear as MFMA GEMM, 512 blocks x 64 rows (unchanged from R7).
// ---------------------------------------------------------------------------
__global__ __launch_bounds__(256) void linear_mfma_kernel(
    const ushort* __restrict__ ctx_hi, const ushort* __restrict__ ctx_lo,
    const ushort* __restrict__ w_hi, const ushort* __restrict__ w_lo,
    const float* __restrict__ bias, float* __restrict__ out)
{
    __shared__ ushort ahi[64 * 136];
    __shared__ ushort alo[64 * 136];

    int tid  = threadIdx.x;
    int lane = tid & 63, wid = tid >> 6;
    int lm = lane & 15, kb = lane >> 4;
    size_t rowbase = (size_t)blockIdx.x * 64;

    for (int idx = tid; idx < 1024; idx += 256) {
        int row = idx >> 4, c16 = idx & 15;
        short8 vh = *(const short8*)(ctx_hi + (rowbase + row) * 128 + c16 * 8);
        short8 vl = *(const short8*)(ctx_lo + (rowbase + row) * 128 + c16 * 8);
        *(short8*)(ahi + row * 136 + c16 * 8) = vh;
        *(short8*)(alo + row * 136 + c16 * 8) = vl;
    }
    __syncthreads();

    floatx4 acc[8];
#pragma unroll
    for (int i = 0; i < 8; i++) acc[i] = (floatx4){0.f, 0.f, 0.f, 0.f};

    const ushort* arow_h = ahi + (wid * 16 + lm) * 136 + kb * 8;
    const ushort* arow_l = alo + (wid * 16 + lm) * 136 + kb * 8;

#pragma unroll
    for (int kstep = 0; kstep < 4; kstep++) {
        short8 afh = *(const short8*)(arow_h + kstep * 32);
        short8 afl = *(const short8*)(arow_l + kstep * 32);
        short8 bfh[8], bfl[8];
#pragma unroll
        for (int nf = 0; nf < 8; nf++) {
            bfh[nf] = *(const short8*)(w_hi + (size_t)(nf * 16 + lm) * 128 + kstep * 32 + kb * 8);
            bfl[nf] = *(const short8*)(w_lo + (size_t)(nf * 16 + lm) * 128 + kstep * 32 + kb * 8);
        }
#pragma unroll
        for (int nf = 0; nf < 8; nf++) {
            acc[nf] = __builtin_amdgcn_mfma_f32_16x16x32_bf16(afh, bfh[nf], acc[nf], 0, 0, 0);
            acc[nf] = __builtin_amdgcn_mfma_f32_16x16x32_bf16(afl, bfh[nf], acc[nf], 0, 0, 0);
            acc[nf] = __builtin_amdgcn_mfma_f32_16x16x32_bf16(afh, bfl[nf], acc[nf], 0, 0, 0);
        }
    }

#pragma unroll
    for (int nf = 0; nf < 8; nf++) {
        int col = nf * 16 + lm;
        float bv = bias[col];
#pragma unroll
        for (int r = 0; r < 4; r++) {
            int row = wid * 16 + kb * 4 + r;
            out[(rowbase + row) * 128 + col] = acc[nf][r] + bv;
        }
    }
}

// ---------------------------------------------------------------------------
extern "C" void kernel_launch(void* const* d_in, const int* in_sizes, int n_in,
                              void* d_out, int out_size, void* d_ws, size_t ws_size,
                              hipStream_t stream)
{
    const float* query = (const float*)d_in[0];
    const float* key   = (const float*)d_in[1];
    const float* value = (const float*)d_in[2];
    const float* ckw   = (const float*)d_in[3];
    const float* ckb   = (const float*)d_in[4];
    const float* cvw   = (const float*)d_in[5];
    const float* cvb   = (const float*)d_in[6];
    const float* lw    = (const float*)d_in[7];
    const float* lb    = (const float*)d_in[8];
    const int*   isamp = (const int*)d_in[9];
    float* out = (float*)d_out;
    float* ws  = (float*)d_ws;

    const size_t NBSD = (size_t)B_ * S_ * D_;   // 4,194,304 floats
    float* q_h  = ws;                   // (B,H,S,DK)
    float* kbuf = ws + NBSD;            // overlaid by ctx hi/lo
    float* k_h  = ws + 2 * NBSD;        // (B,H,S,DK)
    float* v_h  = ws + 3 * NBSD;        // (B,H,S,DK)
    int*   sel  = (int*)(ws + 4 * NBSD);        // (unused, layout kept)
    ushort* wk_hi = (ushort*)(sel + B_ * H_ * NT_);   // [7][256][256] bf16 each
    ushort* wk_lo = wk_hi + 7 * 65536;
    ushort* wv_hi = wk_lo + 7 * 65536;
    ushort* lw_hi = wv_hi + 7 * 65536;  // [128][128]
    ushort* lw_lo = lw_hi + 16384;
    float*  trig  = (float*)(lw_lo + 16384);    // [256][64][2]
    ushort* khi_t = (ushort*)(trig + 32768);    // (B,D,S) bf16
    ushort* klo_t = khi_t + NBSD;
    ushort* vhi_t = klo_t + NBSD;
    ushort* ctx_hi = (ushort*)kbuf;
    ushort* ctx_lo = ctx_hi + NBSD;

    wprep_kernel<<<dim3(1920), 256, 0, stream>>>(ckw, cvw, lw, wk_hi, wk_lo,
                                                 wv_hi, lw_hi, lw_lo, trig);
    rotcvt_kernel<<<dim3(B_, 4, 3), 256, 0, stream>>>(query, key, value, trig,
                                                      q_h, khi_t, klo_t, vhi_t);
    conv6_kernel<<<dim3(B_, 2, 2), 256, 0, stream>>>(khi_t, klo_t, vhi_t,
                                                     wk_hi, wk_lo, wv_hi,
                                                     ckb, cvb, k_h, v_h);
    topk_attn_kernel<<<dim3(B_ * H_), 256, 0, stream>>>(q_h, k_h, v_h, isamp,
                                                        ctx_hi, ctx_lo);
    linear_mfma_kernel<<<dim3(512), 256, 0, stream>>>(ctx_hi, ctx_lo, lw_hi,
                                                      lw_lo, lb, out);
}

// Round 9
// 281.513 us; speedup vs baseline: 1.0947x; 1.0947x over previous
//
#include <hip/hip_runtime.h>
#include <math.h>

// Problem constants
constexpr int B_  = 128;
constexpr int S_  = 256;
constexpr int D_  = 128;   // d_model
constexpr int H_  = 8;
constexpr int DK_ = 16;
constexpr int SK_ = 30;    // SAMPLE_K
constexpr int NT_ = 30;    // N_TOP

typedef short short8  __attribute__((ext_vector_type(8)));
typedef float floatx4 __attribute__((ext_vector_type(4)));

__device__ inline ushort bf16_rne(float f) {
    unsigned u = __float_as_uint(f);
    u += 0x7fffu + ((u >> 16) & 1u);
    return (ushort)(u >> 16);
}
__device__ inline float bf16_to_f(ushort h) {
    return __uint_as_float(((unsigned)h) << 16);
}

// ---------------------------------------------------------------------------
// K0: W prep + trig, t-major (unchanged from R7, passing).
// ---------------------------------------------------------------------------
__global__ __launch_bounds__(256) void wprep_kernel(
    const float* __restrict__ wk, const float* __restrict__ wv,
    const float* __restrict__ lw,
    ushort* __restrict__ wk_hi, ushort* __restrict__ wk_lo,
    ushort* __restrict__ wv_hi,
    ushort* __restrict__ lw_hi, ushort* __restrict__ lw_lo,
    float* __restrict__ trig)
{
    int tid = blockIdx.x * 256 + threadIdx.x;   // grid 1920 -> 0..491519
    if (tid < 458752) {                         // 7*65536 conv weights
        int t  = tid >> 16;                     // 0..6
        int oi = tid & 65535;                   // o*256 + i
        float fk = wk[(size_t)oi * 7 + t];
        ushort hk = bf16_rne(fk);
        wk_hi[tid] = hk;                        // tid == t*65536 + oi
        wk_lo[tid] = bf16_rne(fk - bf16_to_f(hk));
        wv_hi[tid] = bf16_rne(wv[(size_t)oi * 7 + t]);
    } else if (tid < 475136) {                  // lin_w
        int ec = tid - 458752;                  // e*128 + c
        float f = lw[ec];
        ushort hi = bf16_rne(f);
        lw_hi[ec] = hi;
        lw_lo[ec] = bf16_rne(f - bf16_to_f(hi));
    } else {                                    // trig table (double)
        int t2 = tid - 475136;                  // 0..16383
        int f = t2 & 63, l = t2 >> 6;
        double freq = exp(((double)(-f) / 64.0) * 9.210340371976184); // ln(1e4)
        double ang  = (double)l * freq;
        trig[t2 * 2]     = (float)cos(ang);
        trig[t2 * 2 + 1] = (float)sin(ang);
    }
}

// ---------------------------------------------------------------------------
// K1: fused rotary + transpose + bf16 hi/lo convert (unchanged from R7).
// ---------------------------------------------------------------------------
__global__ __launch_bounds__(256) void rotcvt_kernel(
    const float* __restrict__ q, const float* __restrict__ k,
    const float* __restrict__ value, const float* __restrict__ trig,
    float* __restrict__ q_h,
    ushort* __restrict__ khi_t, ushort* __restrict__ klo_t,
    ushort* __restrict__ vhi_t)
{
    __shared__ float tile[64 * 132];   // 64 l x 128 d, pad 4
    int b  = blockIdx.x;
    int lc = blockIdx.y;               // l-chunk of 64
    int ph = blockIdx.z;               // 0=q, 1=k, 2=v
    int tid = threadIdx.x;

    if (ph == 0) {
        for (int s = tid; s < 2048; s += 256) {
            int l = s >> 5, c4 = s & 31;
            int lg = lc * 64 + l;
            float4 qv = *(const float4*)(q + (((size_t)b * 256) + lg) * 128 + c4 * 4);
            float4 tg = *(const float4*)(trig + ((size_t)lg * 64 + 2 * c4) * 2);
            float r0 = qv.x * tg.x - qv.y * tg.y;
            float i0 = qv.x * tg.y + qv.y * tg.x;
            float r1 = qv.z * tg.z - qv.w * tg.w;
            float i1 = qv.z * tg.w + qv.w * tg.z;
            int h = c4 >> 2, dk = (c4 & 3) * 4;
            *(float4*)(q_h + (((size_t)b * 8 + h) * 256 + lg) * 16 + dk) =
                make_float4(r0, i0, r1, i1);
        }
        return;
    }

    if (ph == 1) {
        for (int s = tid; s < 2048; s += 256) {
            int l = s >> 5, c4 = s & 31;
            int lg = lc * 64 + l;
            float4 kv = *(const float4*)(k + (((size_t)b * 256) + lg) * 128 + c4 * 4);
            float4 tg = *(const float4*)(trig + ((size_t)lg * 64 + 2 * c4) * 2);
            float r0 = kv.x * tg.x - kv.y * tg.y;
            float i0 = kv.x * tg.y + kv.y * tg.x;
            float r1 = kv.z * tg.z - kv.w * tg.w;
            float i1 = kv.z * tg.w + kv.w * tg.z;
            *(float4*)(tile + l * 132 + c4 * 4) = make_float4(r0, i0, r1, i1);
        }
        __syncthreads();
        int d = tid >> 1, half = tid & 1;
        alignas(16) ushort hh[32], ll[32];
#pragma unroll
        for (int j = 0; j < 32; j++) {
            float f = tile[(half * 32 + j) * 132 + d];
            ushort hb = bf16_rne(f);
            hh[j] = hb;
            ll[j] = bf16_rne(f - bf16_to_f(hb));
        }
        size_t off = (((size_t)b * 128) + d) * 256 + lc * 64 + half * 32;
#pragma unroll
        for (int m = 0; m < 4; m++) ((uint4*)(khi_t + off))[m] = ((uint4*)hh)[m];
#pragma unroll
        for (int m = 0; m < 4; m++) ((uint4*)(klo_t + off))[m] = ((uint4*)ll)[m];
        return;
    }

    // ph == 2: v
    for (int s = tid; s < 2048; s += 256) {
        int l = s >> 5, c4 = s & 31;
        *(float4*)(tile + l * 132 + c4 * 4) =
            *(const float4*)(value + (((size_t)b * 256) + lc * 64 + l) * 128 + c4 * 4);
    }
    __syncthreads();
    {
        int d = tid >> 1, half = tid & 1;
        alignas(16) ushort hh[32];
#pragma unroll
        for (int j = 0; j < 32; j++)
            hh[j] = bf16_rne(tile[(half * 32 + j) * 132 + d]);
        size_t off = (((size_t)b * 128) + d) * 256 + lc * 64 + half * 32;
#pragma unroll
        for (int m = 0; m < 4; m++) ((uint4*)(vhi_t + off))[m] = ((uint4*)hh)[m];
    }
}

// ---------------------------------------------------------------------------
// K2: conv7 = conv5's exact per-wave tile/order, o-split for occupancy.
//  Wave = 64d x 64o (4x4 frags), block = 2 waves covering 128 o, grid
//  (128 b, {2 dblk x 2 osplit}, 2 kv) = 2048 blocks x 128 thr.  LDS 20 KB
//  -> up to 8 blocks/CU (reg-limited ~6) = ~12 waves/CU, vs conv5's 8.
//  Per-wave instruction stream and accumulation order (ic->ks->t, hh/lh/hl)
//  are IDENTICAL to conv5 -> k_h bitwise unchanged -> top-k stable.
//  Cost: x staged once per (b,dblk,osplit) = 2x conv5's x traffic (L2-hit).
// ---------------------------------------------------------------------------
__global__ __launch_bounds__(128) void conv7_kernel(
    const ushort* __restrict__ khi_t, const ushort* __restrict__ klo_t,
    const ushort* __restrict__ vhi_t,
    const ushort* __restrict__ wk_hi, const ushort* __restrict__ wk_lo,
    const ushort* __restrict__ wv_hi,
    const float* __restrict__ kbias, const float* __restrict__ vbias,
    float* __restrict__ k_h, float* __restrict__ v_h)
{
    constexpr int LI = 72;                 // 64 i + 8 pad (16B-aligned rows)
    __shared__ ushort xhi[70 * LI];
    __shared__ ushort xlo[70 * LI];

    const bool kp = (blockIdx.z == 0);
    const ushort* xg   = kp ? khi_t : vhi_t;
    const ushort* whi  = kp ? wk_hi : wv_hi;
    const float*  bias = kp ? kbias : vbias;
    float* yh          = kp ? k_h : v_h;

    int b    = blockIdx.x;
    int dblk = blockIdx.y >> 1;            // 64-d slice
    int osp  = blockIdx.y & 1;             // 128-o slice
    int tid  = threadIdx.x;                // 0..127
    int lane = tid & 63, wid = tid >> 6;   // wave owns o-range osp*128+wid*64
    int lm = lane & 15, kb = lane >> 4;
    int obase = osp * 128 + wid * 64;

    floatx4 acc[16];                       // [po(4)][nd(4)]
#pragma unroll
    for (int i = 0; i < 16; i++) acc[i] = (floatx4){0.f, 0.f, 0.f, 0.f};

    const short8 zero8 = {0, 0, 0, 0, 0, 0, 0, 0};

    for (int ic = 0; ic < 4; ic++) {
        __syncthreads();
        // stage 70 d-rows (causal-shifted by 6) x 64 i: pure 16B copies
        for (int s = tid; s < 560; s += 128) {
            int r = s >> 3, p = s & 7;
            int gd = dblk * 64 - 6 + r;            // < 128 always
            size_t g = (((size_t)b * 128) + gd) * 256 + ic * 64 + p * 8;
            short8 vh = (gd >= 0) ? *(const short8*)(xg + g) : zero8;
            *(short8*)(xhi + r * LI + p * 8) = vh;
            if (kp) {
                short8 vl = (gd >= 0) ? *(const short8*)(klo_t + g) : zero8;
                *(short8*)(xlo + r * LI + p * 8) = vl;
            }
        }
        __syncthreads();
#pragma unroll
        for (int ks = 0; ks < 2; ks++) {
            int ibase = ic * 64 + ks * 32 + kb * 8;
#pragma unroll
            for (int t = 0; t < 7; t++) {
                short8 xh[4], xl[4];
#pragma unroll
                for (int nd = 0; nd < 4; nd++) {
                    int arow = (nd * 16 + lm + t) * LI + ks * 32 + kb * 8;
                    xh[nd] = *(const short8*)(xhi + arow);
                    if (kp) xl[nd] = *(const short8*)(xlo + arow);
                }
                short8 wh[4], wl[4];
#pragma unroll
                for (int po = 0; po < 4; po++) {
                    size_t woff = (size_t)t * 65536
                                + (size_t)(obase + po * 16 + lm) * 256 + ibase;
                    wh[po] = *(const short8*)(whi + woff);
                    if (kp) wl[po] = *(const short8*)(wk_lo + woff);
                }
#pragma unroll
                for (int po = 0; po < 4; po++) {
#pragma unroll
                    for (int nd = 0; nd < 4; nd++) {
                        int a = po * 4 + nd;
                        acc[a] = __builtin_amdgcn_mfma_f32_16x16x32_bf16(xh[nd], wh[po], acc[a], 0, 0, 0);
                        if (kp) {
                            acc[a] = __builtin_amdgcn_mfma_f32_16x16x32_bf16(xl[nd], wh[po], acc[a], 0, 0, 0);
                            acc[a] = __builtin_amdgcn_mfma_f32_16x16x32_bf16(xh[nd], wl[po], acc[a], 0, 0, 0);
                        }
                    }
                }
            }
        }
    }

    // epilogue: d = dblk*64 + nd*16 + kb*4 + r -> dhi = dblk*4+nd, dk = kb*4+r
#pragma unroll
    for (int po = 0; po < 4; po++) {
        int o = obase + po * 16 + lm;
        float bv = bias[o];
#pragma unroll
        for (int nd = 0; nd < 4; nd++) {
            int dhi = dblk * 4 + nd;
#pragma unroll
            for (int r = 0; r < 4; r++) {
                int dk = kb * 4 + r;
                yh[(((size_t)b * 8 + dhi) * 256 + o) * 16 + dk] = acc[po * 4 + nd][r] + bv;
            }
        }
    }
}

// ---------------------------------------------------------------------------
// K3: fused topk + attention + context assembly.  Same math/order as R7
//  (bitwise-identical outputs); staging vectorized to float4.
// ---------------------------------------------------------------------------
__global__ __launch_bounds__(256) void topk_attn_kernel(
    const float* __restrict__ q_h, const float* __restrict__ k_h,
    const float* __restrict__ v_h, const int* __restrict__ idxs,
    ushort* __restrict__ ctx_hi, ushort* __restrict__ ctx_lo)
{
    __shared__ float ks[S_ * 20];
    __shared__ float vs[S_ * 20];
    __shared__ float Marr[S_];
    __shared__ float qs[NT_][16];
    __shared__ float partial[16][17];
    __shared__ float vmean_s[16];
    __shared__ int sel_s[NT_];
    __shared__ int selflag[S_];
    __shared__ int cnt;

    int bh = blockIdx.x, b = bh >> 3, h = bh & 7;
    int tid = threadIdx.x;
    if (tid == 0) cnt = 0;
    selflag[tid] = 0;

    const float* kp = k_h + (size_t)bh * S_ * DK_;
    const float* vp = v_h + (size_t)bh * S_ * DK_;
    for (int idx = tid; idx < S_ * DK_ / 4; idx += 256) {
        int r = idx >> 2, c4 = idx & 3;
        *(float4*)(ks + r * 20 + c4 * 4) = *(const float4*)(kp + idx * 4);
        *(float4*)(vs + r * 20 + c4 * 4) = *(const float4*)(vp + idx * 4);
    }

    float qr[16];
    const float4* qp = (const float4*)(q_h + ((size_t)bh * S_ + tid) * DK_);
#pragma unroll
    for (int i = 0; i < 4; i++) {
        float4 t4 = qp[i];
        qr[4*i] = t4.x; qr[4*i+1] = t4.y; qr[4*i+2] = t4.z; qr[4*i+3] = t4.w;
    }
    int idxr[SK_];
    const int* ip = idxs + tid * SK_;
#pragma unroll
    for (int s = 0; s < SK_; s++) idxr[s] = ip[s];
    __syncthreads();

    float mx = -1e30f, sm = 0.f;
#pragma unroll
    for (int s = 0; s < SK_; s++) {
        const float4* kr = (const float4*)(ks + idxr[s] * 20);
        float4 k0 = kr[0], k1 = kr[1], k2 = kr[2], k3 = kr[3];
        float d0 = qr[0]*k0.x, d1 = qr[1]*k0.y, d2 = qr[2]*k0.z, d3 = qr[3]*k0.w;
        d0 = fmaf(qr[4],  k1.x, d0); d1 = fmaf(qr[5],  k1.y, d1);
        d2 = fmaf(qr[6],  k1.z, d2); d3 = fmaf(qr[7],  k1.w, d3);
        d0 = fmaf(qr[8],  k2.x, d0); d1 = fmaf(qr[9],  k2.y, d1);
        d2 = fmaf(qr[10], k2.z, d2); d3 = fmaf(qr[11], k2.w, d3);
        d0 = fmaf(qr[12], k3.x, d0); d1 = fmaf(qr[13], k3.y, d1);
        d2 = fmaf(qr[14], k3.z, d2); d3 = fmaf(qr[15], k3.w, d3);
        float dot = (d0 + d1) + (d2 + d3);
        mx = fmaxf(mx, dot);
        sm += dot;
    }
    Marr[tid] = mx - sm * (1.0f / 30.0f);

    {
        int dk = tid & 15, chunk = tid >> 4;
        float s = 0.f;
#pragma unroll
        for (int r = 0; r < 16; r++) s += vs[(chunk * 16 + r) * 20 + dk];
        partial[chunk][dk] = s;
    }
    __syncthreads();

    if (tid < 16) {
        float s = 0.f;
#pragma unroll
        for (int c = 0; c < 16; c++) s += partial[c][tid];
        vmean_s[tid] = s * (1.0f / 256.0f);
    }
    {
        float M = Marr[tid];
        int higher = 0;
        for (int j = 0; j < S_; j++) {
            float Mj = Marr[j];
            if (Mj > M || (Mj == M && j < tid)) higher++;
        }
        if (higher < NT_) {
            int slot = atomicAdd(&cnt, 1);
            sel_s[slot] = tid;
            selflag[tid] = 1;
        }
    }
    __syncthreads();

    for (int idx = tid; idx < NT_ * 4; idx += 256) {
        int u = idx >> 2, c4 = idx & 3;
        *(float4*)(&qs[u][c4 * 4]) =
            *(const float4*)(q_h + ((size_t)bh * S_ + sel_s[u]) * DK_ + c4 * 4);
    }
    __syncthreads();

    if (!selflag[tid]) {
        alignas(16) ushort hh[16], ll[16];
#pragma unroll
        for (int i = 0; i < 16; i++) {
            float v = vmean_s[i];
            ushort hb = bf16_rne(v);
            hh[i] = hb;
            ll[i] = bf16_rne(v - bf16_to_f(hb));
        }
        size_t off = ((size_t)(b * S_ + tid)) * D_ + h * DK_;
        ((uint4*)(ctx_hi + off))[0] = ((uint4*)hh)[0];
        ((uint4*)(ctx_hi + off))[1] = ((uint4*)hh)[1];
        ((uint4*)(ctx_lo + off))[0] = ((uint4*)ll)[0];
        ((uint4*)(ctx_lo + off))[1] = ((uint4*)ll)[1];
    }

    int g = tid >> 3, j = tid & 7;
    if (g < NT_) {
        float qreg[16];
        const float4* q4 = (const float4*)qs[g];
#pragma unroll
        for (int i = 0; i < 4; i++) {
            float4 t4 = q4[i];
            qreg[4*i] = t4.x; qreg[4*i+1] = t4.y; qreg[4*i+2] = t4.z; qreg[4*i+3] = t4.w;
        }
        float e[32];
        float mxs = -1e30f;
#pragma unroll
        for (int li = 0; li < 32; li++) {
            int l = j + li * 8;
            const float4* kr = (const float4*)(ks + l * 20);
            float4 k0 = kr[0], k1 = kr[1], k2 = kr[2], k3 = kr[3];
            float d0 = qreg[0]*k0.x, d1 = qreg[1]*k0.y, d2 = qreg[2]*k0.z, d3 = qreg[3]*k0.w;
            d0 = fmaf(qreg[4],  k1.x, d0); d1 = fmaf(qreg[5],  k1.y, d1);
            d2 = fmaf(qreg[6],  k1.z, d2); d3 = fmaf(qreg[7],  k1.w, d3);
            d0 = fmaf(qreg[8],  k2.x, d0); d1 = fmaf(qreg[9],  k2.y, d1);
            d2 = fmaf(qreg[10], k2.z, d2); d3 = fmaf(qreg[11], k2.w, d3);
            d0 = fmaf(qreg[12], k3.x, d0); d1 = fmaf(qreg[13], k3.y, d1);
            d2 = fmaf(qreg[14], k3.z, d2); d3 = fmaf(qreg[15], k3.w, d3);
            e[li] = ((d0 + d1) + (d2 + d3)) * 0.25f;
            mxs = fmaxf(mxs, e[li]);
        }
        mxs = fmaxf(mxs, __shfl_xor(mxs, 1));
        mxs = fmaxf(mxs, __shfl_xor(mxs, 2));
        mxs = fmaxf(mxs, __shfl_xor(mxs, 4));
        float se = 0.f;
#pragma unroll
        for (int li = 0; li < 32; li++) {
            e[li] = __expf(e[li] - mxs);
            se += e[li];
        }
        se += __shfl_xor(se, 1);
        se += __shfl_xor(se, 2);
        se += __shfl_xor(se, 4);
        float inv = 1.0f / se;

        int dk0 = j * 2;
        int gbase = tid & 56;
        float o0 = 0.f, o1 = 0.f;
        for (int li = 0; li < 32; li++) {
#pragma unroll
            for (int m = 0; m < 8; m++) {
                float p = __shfl(e[li], gbase | m);
                float2 vv = *(const float2*)(vs + (li * 8 + m) * 20 + dk0);
                o0 = fmaf(p, vv.x, o0);
                o1 = fmaf(p, vv.y, o1);
            }
        }
        int lrow = sel_s[g];
        float v0 = o0 * inv, v1 = o1 * inv;
        ushort h0 = bf16_rne(v0), h1 = bf16_rne(v1);
        ushort l0 = bf16_rne(v0 - bf16_to_f(h0));
        ushort l1 = bf16_rne(v1 - bf16_to_f(h1));
        size_t off = ((size_t)(b * S_ + lrow)) * D_ + h * DK_ + dk0;
        *(uint*)(ctx_hi + off) = (uint)h0 | ((uint)h1 << 16);
        *(uint*)(ctx_lo + off) = (uint)l0 | ((uint)l1 << 16);
    }
}

// ---------------------------------------------------------------------------
// K4: final linear as MFMA GEMM, 512 blocks x 64 rows (unchanged from R7).
// ---------------------------------------------------------------------------
__global__ __launch_bounds__(256) void linear_mfma_kernel(
    const ushort* __restrict__ ctx_hi, const ushort* __restrict__ ctx_lo,
    const ushort* __restrict__ w_hi, const ushort* __restrict__ w_lo,
    const float* __restrict__ bias, float* __restrict__ out)
{
    __shared__ ushort ahi[64 * 136];
    __shared__ ushort alo[64 * 136];

    int tid  = threadIdx.x;
    int lane = tid & 63, wid = tid >> 6;
    int lm = lane & 15, kb = lane >> 4;
    size_t rowbase = (size_t)blockIdx.x * 64;

    for (int idx = tid; idx < 1024; idx += 256) {
        int row = idx >> 4, c16 = idx & 15;
        short8 vh = *(const short8*)(ctx_hi + (rowbase + row) * 128 + c16 * 8);
        short8 vl = *(const short8*)(ctx_lo + (rowbase + row) * 128 + c16 * 8);
        *(short8*)(ahi + row * 136 + c16 * 8) = vh;
        *(short8*)(alo + row * 136 + c16 * 8) = vl;
    }
    __syncthreads();

    floatx4 acc[8];
#pragma unroll
    for (int i = 0; i < 8; i++) acc[i] = (floatx4){0.f, 0.f, 0.f, 0.f};

    const ushort* arow_h = ahi + (wid * 16 + lm) * 136 + kb * 8;
    const ushort* arow_l = alo + (wid * 16 + lm) * 136 + kb * 8;

#pragma unroll
    for (int kstep = 0; kstep < 4; kstep++) {
        short8 afh = *(const short8*)(arow_h + kstep * 32);
        short8 afl = *(const short8*)(arow_l + kstep * 32);
        short8 bfh[8], bfl[8];
#pragma unroll
        for (int nf = 0; nf < 8; nf++) {
            bfh[nf] = *(const short8*)(w_hi + (size_t)(nf * 16 + lm) * 128 + kstep * 32 + kb * 8);
            bfl[nf] = *(const short8*)(w_lo + (size_t)(nf * 16 + lm) * 128 + kstep * 32 + kb * 8);
        }
#pragma unroll
        for (int nf = 0; nf < 8; nf++) {
            acc[nf] = __builtin_amdgcn_mfma_f32_16x16x32_bf16(afh, bfh[nf], acc[nf], 0, 0, 0);
            acc[nf] = __builtin_amdgcn_mfma_f32_16x16x32_bf16(afl, bfh[nf], acc[nf], 0, 0, 0);
            acc[nf] = __builtin_amdgcn_mfma_f32_16x16x32_bf16(afh, bfl[nf], acc[nf], 0, 0, 0);
        }
    }

#pragma unroll
    for (int nf = 0; nf < 8; nf++) {
        int col = nf * 16 + lm;
        float bv = bias[col];
#pragma unroll
        for (int r = 0; r < 4; r++) {
            int row = wid * 16 + kb * 4 + r;
            out[(rowbase + row) * 128 + col] = acc[nf][r] + bv;
        }
    }
}

// ---------------------------------------------------------------------------
extern "C" void kernel_launch(void* const* d_in, const int* in_sizes, int n_in,
                              void* d_out, int out_size, void* d_ws, size_t ws_size,
                              hipStream_t stream)
{
    const float* query = (const float*)d_in[0];
    const float* key   = (const float*)d_in[1];
    const float* value = (const float*)d_in[2];
    const float* ckw   = (const float*)d_in[3];
    const float* ckb   = (const float*)d_in[4];
    const float* cvw   = (const float*)d_in[5];
    const float* cvb   = (const float*)d_in[6];
    const float* lw    = (const float*)d_in[7];
    const float* lb    = (const float*)d_in[8];
    const int*   isamp = (const int*)d_in[9];
    float* out = (float*)d_out;
    float* ws  = (float*)d_ws;

    const size_t NBSD = (size_t)B_ * S_ * D_;   // 4,194,304 floats
    float* q_h  = ws;                   // (B,H,S,DK)
    float* kbuf = ws + NBSD;            // overlaid by ctx hi/lo
    float* k_h  = ws + 2 * NBSD;        // (B,H,S,DK)
    float* v_h  = ws + 3 * NBSD;        // (B,H,S,DK)
    int*   sel  = (int*)(ws + 4 * NBSD);        // (unused, layout kept)
    ushort* wk_hi = (ushort*)(sel + B_ * H_ * NT_);   // [7][256][256] bf16 each
    ushort* wk_lo = wk_hi + 7 * 65536;
    ushort* wv_hi = wk_lo + 7 * 65536;
    ushort* lw_hi = wv_hi + 7 * 65536;  // [128][128]
    ushort* lw_lo = lw_hi + 16384;
    float*  trig  = (float*)(lw_lo + 16384);    // [256][64][2]
    ushort* khi_t = (ushort*)(trig + 32768);    // (B,D,S) bf16
    ushort* klo_t = khi_t + NBSD;
    ushort* vhi_t = klo_t + NBSD;
    ushort* ctx_hi = (ushort*)kbuf;
    ushort* ctx_lo = ctx_hi + NBSD;

    wprep_kernel<<<dim3(1920), 256, 0, stream>>>(ckw, cvw, lw, wk_hi, wk_lo,
                                                 wv_hi, lw_hi, lw_lo, trig);
    rotcvt_kernel<<<dim3(B_, 4, 3), 256, 0, stream>>>(query, key, value, trig,
                                                      q_h, khi_t, klo_t, vhi_t);
    conv7_kernel<<<dim3(B_, 4, 2), 128, 0, stream>>>(khi_t, klo_t, vhi_t,
                                                     wk_hi, wk_lo, wv_hi,
                                                     ckb, cvb, k_h, v_h);
    topk_attn_kernel<<<dim3(B_ * H_), 256, 0, stream>>>(q_h, k_h, v_h, isamp,
                                                        ctx_hi, ctx_lo);
    linear_mfma_kernel<<<dim3(512), 256, 0, stream>>>(ctx_hi, ctx_lo, lw_hi,
                                                      lw_lo, lb, out);
}